// Round 8
// baseline (146.718 us; speedup 1.0000x reference)
//
#include <hip/hip_runtime.h>
#include <hip/hip_bf16.h>
#include <math.h>

#define BB 4
#define NN 4096
#define CCH 256
#define HEADS 8
#define HD 32
#define NKV 1024
#define EPS_LN 1e-5f

typedef short short8 __attribute__((ext_vector_type(8)));
typedef float floatx4 __attribute__((ext_vector_type(4)));

// scale = HD^-0.5 folded with log2(e): softmax runs in exp2 domain
#define QSCALE (0.17677669529663687f * 1.4426950408889634f)

__device__ __forceinline__ unsigned pk_bf16(float a, float b) {
  __hip_bfloat162 h = __float22bfloat162_rn(make_float2(a, b));
  unsigned u; __builtin_memcpy(&u, &h, 4); return u;
}

__device__ __forceinline__ short8 cvt8(float4 a, float4 b) {
  union { short8 s; unsigned u[4]; } r;
  r.u[0] = pk_bf16(a.x, a.y); r.u[1] = pk_bf16(a.z, a.w);
  r.u[2] = pk_bf16(b.x, b.y); r.u[3] = pk_bf16(b.z, b.w);
  return r.s;
}

// ---------------------------------------------------------------------------
// Cast weights fp32 -> bf16, FRAGMENT-MAJOR swizzle:
// unit(row,col) = ((row>>4)*(Kd/32) + (col>>5))*64 + ((col>>3)&3)*16 + (row&15)
// -> a wave's wf load is one contiguous 1KB segment. QSCALE folded into q_w.
// sr_w additionally gets K permuted to QUADRANT-MAJOR: col' = q*256 + c.
// ---------------------------------------------------------------------------
__global__ __launch_bounds__(256) void cast_weights(
    const float* __restrict__ q_w, const float* __restrict__ kv_w,
    const float* __restrict__ sr_w, const float* __restrict__ proj_w,
    unsigned short* __restrict__ q_wbf, unsigned short* __restrict__ kv_wbf,
    unsigned short* __restrict__ sr_wbf, unsigned short* __restrict__ proj_wbf) {
  const int e = (blockIdx.x * 256 + threadIdx.x) * 8;
  if (e >= 196608 && e < 458752) {
    // sr_w: 8 consecutive src elems = (row, c0..c0+1, q0..3), c0 even
    const int off = e - 196608;
    const int row = off >> 10;
    const int wr = off & 1023;
    const int c0 = (wr >> 3) * 2;
    float4 a = *(const float4*)&sr_w[off];
    float4 b = *(const float4*)&sr_w[off + 4];
    const float v[8] = {a.x, a.y, a.z, a.w, b.x, b.y, b.z, b.w};
    const int base = (row >> 4) * 32;   // Kd/32 = 32
#pragma unroll
    for (int q = 0; q < 4; ++q) {
      const int unit = (base + q * 8 + (c0 >> 5)) * 64 + ((c0 >> 3) & 3) * 16 + (row & 15);
      *(unsigned*)&sr_wbf[unit * 8 + (c0 & 7)] = pk_bf16(v[q], v[4 + q]);
    }
    return;
  }
  const float* src; unsigned short* dst; int off; float sc = 1.f;
  if (e < 65536)       { src = q_w;    dst = q_wbf;    off = e;          sc = QSCALE; }
  else if (e < 196608) { src = kv_w;   dst = kv_wbf;   off = e - 65536; }
  else                 { src = proj_w; dst = proj_wbf; off = e - 458752; }
  const int row = off >> 8;
  const int col = off & 255;
  const int unit = ((row >> 4) * 8 + (col >> 5)) * 64 + ((col >> 3) & 3) * 16 + (row & 15);
  float4 a = *(const float4*)&src[off];
  float4 b = *(const float4*)&src[off + 4];
  a.x *= sc; a.y *= sc; a.z *= sc; a.w *= sc;
  b.x *= sc; b.y *= sc; b.z *= sc; b.w *= sc;
  *(short8*)&dst[unit * 8] = cvt8(a, b);
}

// X-tile LDS layout (tokens x 32 16B-units, 33-unit skew)
#define XU16(t, u) (((t) * 33 + (u)) * 8)

// ---------------------------------------------------------------------------
// SR-conv + LN + KV projection (unchanged from R7 -- control).
// Grid 256 x 512 thr (8 waves): conv 2 ct/wave full-K, LN on tid<256,
// KV waves 0-3 -> K, 4-7 -> V.
// ---------------------------------------------------------------------------
__global__ __launch_bounds__(512) void qconv_gemm(const float* __restrict__ x,
    const unsigned short* __restrict__ sr_wbf, const float* __restrict__ sr_b,
    const float* __restrict__ ln_g, const float* __restrict__ ln_b,
    const unsigned short* __restrict__ kv_wbf, const float* __restrict__ kv_b,
    unsigned short* __restrict__ kbf, unsigned short* __restrict__ vtbf) {
  __shared__ unsigned short sm[20736];
  const int tid = threadIdx.x, w = tid >> 6, ln = tid & 63;
  const int l15 = ln & 15, qd = ln >> 4;
  unsigned short* xs = sm + 16512;
  const int gt0 = blockIdx.x * 16;
  const int b = gt0 >> 10, tl = gt0 & 1023;
  const int ti = (tl & 1023) >> 5;
  const int cbase = 2 * (tl & 31);
#pragma unroll
  for (int it = 0; it < 4; ++it) {
    const int g = it * 512 + tid;     // 0..2047 16B-units
    const int xt = g >> 5, u = g & 31;
    const int di = xt >> 5, cj = xt & 31;
    const int row = (2 * ti + di) * 64 + cbase + cj;
    const float* s = &x[((size_t)b * NN + row) * CCH + u * 8];
    float4 a = *(const float4*)s;
    float4 b2 = *(const float4*)(s + 4);
    const int tk = cj >> 1, q = di * 2 + (cj & 1);
    *(short8*)(sm + (tk * 129 + q * 32 + u) * 8) = cvt8(a, b2);
  }
  __syncthreads();
  floatx4 cacc[2];
#pragma unroll
  for (int ct = 0; ct < 2; ++ct) for (int r = 0; r < 4; ++r) cacc[ct][r] = 0.f;
  const unsigned short* wbc = sr_wbf + ln * 8;
#pragma unroll
  for (int kc = 0; kc < 32; ++kc) {
    short8 xf = *(const short8*)(sm + (l15 * 129 + kc * 4 + qd) * 8);
#pragma unroll
    for (int ct = 0; ct < 2; ++ct) {
      short8 wf = *(const short8*)(wbc + ((size_t)((w * 2 + ct) * 32 + kc)) * 512);
      cacc[ct] = __builtin_amdgcn_mfma_f32_16x16x32_bf16(wf, xf, cacc[ct], 0, 0, 0);
    }
  }
  __syncthreads();
  float* ft = (float*)sm;
#pragma unroll
  for (int ct = 0; ct < 2; ++ct) {
    float4 o;
    o.x = cacc[ct][0]; o.y = cacc[ct][1]; o.z = cacc[ct][2]; o.w = cacc[ct][3];
    *(float4*)&ft[l15 * 260 + (w * 2 + ct) * 16 + qd * 4] = o;
  }
  __syncthreads();
  if (tid < 256) {
    const int tk = tid >> 4, l16 = tid & 15;
    float v[16];
    float4* vv = (float4*)v;
#pragma unroll
    for (int m = 0; m < 4; ++m) {
      float4 t = *(float4*)&ft[tk * 260 + l16 * 16 + m * 4];
      float4 sb = *(const float4*)&sr_b[l16 * 16 + m * 4];
      t.x += sb.x; t.y += sb.y; t.z += sb.z; t.w += sb.w;
      vv[m] = t;
    }
    float s1 = 0.f, s2 = 0.f;
#pragma unroll
    for (int i = 0; i < 16; ++i) { s1 += v[i]; s2 += v[i] * v[i]; }
#pragma unroll
    for (int off = 1; off < 16; off <<= 1) {
      s1 += __shfl_xor(s1, off);
      s2 += __shfl_xor(s2, off);
    }
    const float mu = s1 * (1.f / 256.f);
    const float rstd = rsqrtf(s2 * (1.f / 256.f) - mu * mu + EPS_LN);
#pragma unroll
    for (int m = 0; m < 2; ++m) {
      float4 ga = *(const float4*)&ln_g[l16 * 16 + m * 8];
      float4 gb = *(const float4*)&ln_g[l16 * 16 + m * 8 + 4];
      float4 ba = *(const float4*)&ln_b[l16 * 16 + m * 8];
      float4 bb = *(const float4*)&ln_b[l16 * 16 + m * 8 + 4];
      float4 oa, ob;
      oa.x = (vv[m * 2].x - mu) * rstd * ga.x + ba.x;
      oa.y = (vv[m * 2].y - mu) * rstd * ga.y + ba.y;
      oa.z = (vv[m * 2].z - mu) * rstd * ga.z + ba.z;
      oa.w = (vv[m * 2].w - mu) * rstd * ga.w + ba.w;
      ob.x = (vv[m * 2 + 1].x - mu) * rstd * gb.x + bb.x;
      ob.y = (vv[m * 2 + 1].y - mu) * rstd * gb.y + bb.y;
      ob.z = (vv[m * 2 + 1].z - mu) * rstd * gb.z + bb.z;
      ob.w = (vv[m * 2 + 1].w - mu) * rstd * gb.w + bb.w;
      *(short8*)(xs + XU16(tk, l16 * 2 + m)) = cvt8(oa, ob);
    }
  }
  __syncthreads();
  const bool isV = (w >= 4);
  const int c16b = (w & 3) * 4;
  floatx4 kacc[4];
#pragma unroll
  for (int ct = 0; ct < 4; ++ct) for (int r = 0; r < 4; ++r) kacc[ct][r] = 0.f;
  const unsigned short* wb = kv_wbf + (size_t)(isV ? 16 + c16b : c16b) * 4096 + ln * 8;
  if (!isV) {
#pragma unroll
    for (int kc = 0; kc < 8; ++kc) {
      short8 xf = *(const short8*)(xs + XU16(l15, kc * 4 + qd));
#pragma unroll
      for (int ct = 0; ct < 4; ++ct) {
        short8 wf = *(const short8*)(wb + ((size_t)ct * 4096 + kc * 512));
        kacc[ct] = __builtin_amdgcn_mfma_f32_16x16x32_bf16(wf, xf, kacc[ct], 0, 0, 0);
      }
    }
    const int tok = tl + l15;
#pragma unroll
    for (int ct = 0; ct < 4; ++ct) {
      const int ch = (c16b + ct) * 16 + qd * 4;
      float4 bb = *(const float4*)&kv_b[ch];
      uint2 u;
      u.x = pk_bf16(kacc[ct][0] + bb.x, kacc[ct][1] + bb.y);
      u.y = pk_bf16(kacc[ct][2] + bb.z, kacc[ct][3] + bb.w);
      const int h = ch >> 5, d0 = ch & 31;
      *(uint2*)&kbf[((size_t)(b * HEADS + h) * NKV + tok) * HD + d0] = u;
    }
  } else {
#pragma unroll
    for (int kc = 0; kc < 8; ++kc) {
      short8 xf = *(const short8*)(xs + XU16(l15, kc * 4 + qd));
#pragma unroll
      for (int ct = 0; ct < 4; ++ct) {
        short8 wf = *(const short8*)(wb + ((size_t)ct * 4096 + kc * 512));
        kacc[ct] = __builtin_amdgcn_mfma_f32_16x16x32_bf16(xf, wf, kacc[ct], 0, 0, 0);
      }
    }
    const int ccv = tl >> 6;
    const int base6 = (tl & 63) + qd * 4;
    const int kg = (base6 >> 5) & 1, kq = (base6 >> 3) & 3, j0 = base6 & 7;
#pragma unroll
    for (int ct = 0; ct < 4; ++ct) {
      const int vc = (w - 4) * 64 + ct * 16 + l15;
      const float bb = kv_b[vc + 256];
      uint2 u;
      u.x = pk_bf16(kacc[ct][0] + bb, kacc[ct][1] + bb);
      u.y = pk_bf16(kacc[ct][2] + bb, kacc[ct][3] + bb);
      const int hh = vc >> 5, d = vc & 31;
      const int half = d >> 4, dl = d & 15;
      const int unit = ((ccv * 2 + kg) * 2 + half) * 64 + kq * 16 + dl;
      *(uint2*)&vtbf[(size_t)(b * HEADS + hh) * 32768 + unit * 8 + j0] = u;
    }
  }
}

// ---------------------------------------------------------------------------
// FUSED Q-projection + flash attention + output projection (v12).
// OCCUPANCY-DOUBLED vs v11: 32 tokens/block, grid 512 x 512 thr, wave = head,
// 2 qt/wave. LDS slimmed 144 -> 51.7 KB: P cut to 2 slots/wave (slot reuse
// across chunks is the SAME WAR pattern the proven v11 kernel already used --
// same-wave in-order DS makes it safe), and Q aliased into the wave's own
// P slot (qf read into regs before any P write; in-order DS => no hazard).
// => 2 blocks/CU, 4 waves/SIMD: double latency hiding for the
// exp2 / LDS-round-trip / L2-load chain. K/V L2 reads double (~1 us at L2 BW).
// LDS map (16B units): X[0,1056) | wave w: P/Q [1056+w*272, +272).
// ---------------------------------------------------------------------------
__global__ __launch_bounds__(512) void attn_proj(
    const float* __restrict__ x,
    const unsigned short* __restrict__ q_wbf, const float* __restrict__ q_b,
    const unsigned short* __restrict__ kbf,
    const unsigned short* __restrict__ vtbf,
    const unsigned short* __restrict__ p_wbf, const float* __restrict__ p_b,
    float* __restrict__ out) {
  __shared__ unsigned short sm[25856];   // 51712 B = 3232 16B-units
  const int tid = threadIdx.x, w = tid >> 6, ln = tid & 63;
  const int l15 = ln & 15, qd = ln >> 4;
  const int g0 = blockIdx.x * 32;
  const int b = g0 >> 12;
  const int bh = b * HEADS + w;
  const unsigned short* kbase = kbf + (size_t)bh * NKV * HD;
  const unsigned short* vfb = vtbf + (size_t)bh * 32768;

  // ---- stage X (32 tokens, fp32 -> bf16, shared by all 8 heads) ----
  const float* Xg = x + (size_t)g0 * 256;
#pragma unroll
  for (int j = 0; j < 2; ++j) {
    const int idx = j * 512 + tid;
    const int tok = idx >> 5, u = idx & 31;
    float4 a = *(const float4*)(Xg + (size_t)tok * 256 + u * 8);
    float4 b2 = *(const float4*)(Xg + (size_t)tok * 256 + u * 8 + 4);
    *(short8*)(sm + XU16(tok, u)) = cvt8(a, b2);
  }
  __syncthreads();

  const int pu = 1056 + w * 272;            // wave-private P/Q base (16B units)
  unsigned short* qls = sm + pu * 8;        // Q aliased into P slot (160 units)

  // ---- Q projection for own head: 32 tok x 32 ch, wave-private ----
  {
    floatx4 qacc[2][2];
#pragma unroll
    for (int tt = 0; tt < 2; ++tt)
#pragma unroll
      for (int ct = 0; ct < 2; ++ct)
        for (int r = 0; r < 4; ++r) qacc[tt][ct][r] = 0.f;
    const unsigned short* wb = q_wbf + (size_t)(2 * w) * 4096 + ln * 8;
#pragma unroll
    for (int kc = 0; kc < 8; ++kc) {
      short8 wf0 = *(const short8*)(wb + kc * 512);
      short8 wf1 = *(const short8*)(wb + (8 + kc) * 512);
#pragma unroll
      for (int tt = 0; tt < 2; ++tt) {
        short8 xf = *(const short8*)(sm + XU16(tt * 16 + l15, kc * 4 + qd));
        qacc[tt][0] = __builtin_amdgcn_mfma_f32_16x16x32_bf16(wf0, xf, qacc[tt][0], 0, 0, 0);
        qacc[tt][1] = __builtin_amdgcn_mfma_f32_16x16x32_bf16(wf1, xf, qacc[tt][1], 0, 0, 0);
      }
    }
#pragma unroll
    for (int tt = 0; tt < 2; ++tt)
#pragma unroll
      for (int ct = 0; ct < 2; ++ct) {
        const int ch = w * 32 + ct * 16 + qd * 4;
        float4 bb = *(const float4*)&q_b[ch];
        uint2 u;
        u.x = pk_bf16(qacc[tt][ct][0] + bb.x * QSCALE, qacc[tt][ct][1] + bb.y * QSCALE);
        u.y = pk_bf16(qacc[tt][ct][2] + bb.z * QSCALE, qacc[tt][ct][3] + bb.w * QSCALE);
        *(uint2*)(qls + ((tt * 16 + l15) * 5 + ct * 2 + (qd >> 1)) * 8 + (qd & 1) * 4) = u;
      }
  }
  // same-wave LDS round trip (in-order DS; qf safely read before P overwrites)
  short8 qf[2];
#pragma unroll
  for (int qt = 0; qt < 2; ++qt)
    qf[qt] = *(const short8*)(qls + ((qt * 16 + l15) * 5 + qd) * 8);

  const short8 ones = {16256, 16256, 16256, 16256, 16256, 16256, 16256, 16256};
  floatx4 a0[2], a1[2], al[2];
#pragma unroll
  for (int qt = 0; qt < 2; ++qt)
#pragma unroll
    for (int r = 0; r < 4; ++r) { a0[qt][r] = 0.f; a1[qt][r] = 0.f; al[qt][r] = 0.f; }

  short8 kfA[4], vA[4], kfB[4], vB[4];
#define LOADKV(KF, VV, CC) do {                                               \
    const unsigned short* kp = kbase + ((size_t)(CC) * 64 + l15) * HD + qd * 8; \
    _Pragma("unroll")                                                          \
    for (int t = 0; t < 4; ++t) (KF)[t] = *(const short8*)(kp + t * 16 * HD);  \
    const unsigned short* vp = vfb + ((size_t)(CC) * 256 + ln) * 8;            \
    _Pragma("unroll")                                                          \
    for (int u = 0; u < 4; ++u) (VV)[u] = *(const short8*)(vp + u * 512);      \
  } while (0)

#define CHUNK(KF, VV) do {                                                     \
    _Pragma("unroll")                                                          \
    for (int qt = 0; qt < 2; ++qt) {                                           \
      const int pq = pu + qt * 136;                                            \
      floatx4 s[4];                                                            \
      _Pragma("unroll")                                                        \
      for (int t = 0; t < 4; ++t) {                                            \
        floatx4 z; for (int r = 0; r < 4; ++r) z[r] = 0.f;                     \
        s[t] = __builtin_amdgcn_mfma_f32_16x16x32_bf16((KF)[t], qf[qt], z, 0, 0, 0); \
      }                                                                        \
      _Pragma("unroll")                                                        \
      for (int t = 0; t < 4; ++t) {                                            \
        uint2 pk;                                                              \
        pk.x = pk_bf16(__builtin_amdgcn_exp2f(s[t][0]), __builtin_amdgcn_exp2f(s[t][1])); \
        pk.y = pk_bf16(__builtin_amdgcn_exp2f(s[t][2]), __builtin_amdgcn_exp2f(s[t][3])); \
        const int unit = pq + (t >> 1) * 68 + ((t & 1) * 2 + (qd >> 1)) * 16 + l15; \
        *(uint2*)(sm + unit * 8 + (qd & 1) * 4) = pk;                          \
      }                                                                        \
      _Pragma("unroll")                                                        \
      for (int kg = 0; kg < 2; ++kg) {                                         \
        short8 pf = *(const short8*)(sm + (pq + kg * 68 + ln) * 8);            \
        a0[qt] = __builtin_amdgcn_mfma_f32_16x16x32_bf16((VV)[kg * 2], pf, a0[qt], 0, 0, 0);     \
        a1[qt] = __builtin_amdgcn_mfma_f32_16x16x32_bf16((VV)[kg * 2 + 1], pf, a1[qt], 0, 0, 0); \
        al[qt] = __builtin_amdgcn_mfma_f32_16x16x32_bf16(ones, pf, al[qt], 0, 0, 0);             \
      }                                                                        \
    }                                                                          \
  } while (0)

  LOADKV(kfA, vA, 0);
  for (int cc = 0; cc < 16; cc += 2) {
    LOADKV(kfB, vB, cc + 1);
    CHUNK(kfA, vA);
    if (cc + 2 < 16) LOADKV(kfA, vA, cc + 2);
    CHUNK(kfB, vB);
  }
#undef LOADKV
#undef CHUNK

  // ---- all waves done with P and X -> stage normalized attn-out into X region
  __syncthreads();
#pragma unroll
  for (int qt = 0; qt < 2; ++qt) {
    const float inv = 1.f / al[qt][0];
    const int t = qt * 16 + l15;
    const int u0 = w * 4 + (qd >> 1);
    uint2 v0, v1;
    v0.x = pk_bf16(a0[qt][0] * inv, a0[qt][1] * inv);
    v0.y = pk_bf16(a0[qt][2] * inv, a0[qt][3] * inv);
    v1.x = pk_bf16(a1[qt][0] * inv, a1[qt][1] * inv);
    v1.y = pk_bf16(a1[qt][2] * inv, a1[qt][3] * inv);
    *(uint2*)(sm + XU16(t, u0) + (qd & 1) * 4) = v0;
    *(uint2*)(sm + XU16(t, u0 + 2) + (qd & 1) * 4) = v1;
  }
  __syncthreads();

  // ---- output projection in-block: wave -> ch-block (w&3), token-half (w>>2)
  const int cb = w & 3, th = w >> 2;
  floatx4 pacc[4];
#pragma unroll
  for (int ct = 0; ct < 4; ++ct) for (int r = 0; r < 4; ++r) pacc[ct][r] = 0.f;
  const unsigned short* wb = p_wbf + (size_t)(cb * 4) * 4096 + ln * 8;
#pragma unroll
  for (int kc = 0; kc < 8; ++kc) {
    short8 xf = *(const short8*)(sm + XU16(th * 16 + l15, kc * 4 + qd));
#pragma unroll
    for (int ct = 0; ct < 4; ++ct) {
      short8 wf = *(const short8*)(wb + (ct * 8 + kc) * 512);
      pacc[ct] = __builtin_amdgcn_mfma_f32_16x16x32_bf16(wf, xf, pacc[ct], 0, 0, 0);
    }
  }
  const int chb = cb * 64;
  {
    const long tok = (long)g0 + th * 16 + l15;
#pragma unroll
    for (int ct = 0; ct < 4; ++ct) {
      const int ch = chb + ct * 16 + qd * 4;
      float4 bb = *(const float4*)&p_b[ch];
      float4 o;
      o.x = pacc[ct][0] + bb.x; o.y = pacc[ct][1] + bb.y;
      o.z = pacc[ct][2] + bb.z; o.w = pacc[ct][3] + bb.w;
      *(float4*)&out[(size_t)tok * 256 + ch] = o;
    }
  }
}

// ---------------------------------------------------------------------------
extern "C" void kernel_launch(void* const* d_in, const int* in_sizes, int n_in,
                              void* d_out, int out_size, void* d_ws, size_t ws_size,
                              hipStream_t stream) {
  const float* x      = (const float*)d_in[0];
  const float* q_w    = (const float*)d_in[1];
  const float* q_b    = (const float*)d_in[2];
  const float* kv_w   = (const float*)d_in[3];
  const float* kv_b   = (const float*)d_in[4];
  const float* sr_w   = (const float*)d_in[5];
  const float* sr_b   = (const float*)d_in[6];
  const float* ln_g   = (const float*)d_in[7];
  const float* ln_b   = (const float*)d_in[8];
  const float* proj_w = (const float*)d_in[9];
  const float* proj_b = (const float*)d_in[10];
  float* out = (float*)d_out;

  char* base = (char*)d_ws;
  const size_t MB = 1048576;
  unsigned short* q_wbf    = (unsigned short*)(base);                 // 128 KB
  unsigned short* kv_wbf   = (unsigned short*)(base + 131072);        // 256 KB
  unsigned short* sr_wbf   = (unsigned short*)(base + 393216);        // 512 KB
  unsigned short* proj_wbf = (unsigned short*)(base + 917504);        // 128 KB
  unsigned short* k_bf     = (unsigned short*)(base + 9 * MB);        // 2 MB
  unsigned short* vt_bf    = (unsigned short*)(base + 11 * MB);       // 2 MB

  cast_weights<<<256, 256, 0, stream>>>(q_w, kv_w, sr_w, proj_w,
                                        q_wbf, kv_wbf, sr_wbf, proj_wbf);
  qconv_gemm<<<256, 512, 0, stream>>>(x, sr_wbf, sr_b, ln_g, ln_b,
                                      kv_wbf, kv_b, k_bf, vt_bf);
  attn_proj<<<512, 512, 0, stream>>>(x, q_wbf, q_b, k_bf, vt_bf,
                                     proj_wbf, proj_b, out);
}

// Round 9
// 140.266 us; speedup vs baseline: 1.0460x; 1.0460x over previous
//
#include <hip/hip_runtime.h>
#include <hip/hip_bf16.h>
#include <math.h>

#define BB 4
#define NN 4096
#define CCH 256
#define HEADS 8
#define HD 32
#define NKV 1024
#define EPS_LN 1e-5f

typedef short short8 __attribute__((ext_vector_type(8)));
typedef float floatx4 __attribute__((ext_vector_type(4)));

// scale = HD^-0.5 folded with log2(e): softmax runs in exp2 domain
#define QSCALE (0.17677669529663687f * 1.4426950408889634f)

__device__ __forceinline__ unsigned pk_bf16(float a, float b) {
  __hip_bfloat162 h = __float22bfloat162_rn(make_float2(a, b));
  unsigned u; __builtin_memcpy(&u, &h, 4); return u;
}

__device__ __forceinline__ short8 cvt8(float4 a, float4 b) {
  union { short8 s; unsigned u[4]; } r;
  r.u[0] = pk_bf16(a.x, a.y); r.u[1] = pk_bf16(a.z, a.w);
  r.u[2] = pk_bf16(b.x, b.y); r.u[3] = pk_bf16(b.z, b.w);
  return r.s;
}

// ---------------------------------------------------------------------------
// Cast weights fp32 -> bf16, FRAGMENT-MAJOR swizzle:
// unit(row,col) = ((row>>4)*(Kd/32) + (col>>5))*64 + ((col>>3)&3)*16 + (row&15)
// -> a wave's wf load is one contiguous 1KB segment. QSCALE folded into q_w.
// sr_w additionally gets K permuted to QUADRANT-MAJOR: col' = q*256 + c.
// ---------------------------------------------------------------------------
__global__ __launch_bounds__(256) void cast_weights(
    const float* __restrict__ q_w, const float* __restrict__ kv_w,
    const float* __restrict__ sr_w, const float* __restrict__ proj_w,
    unsigned short* __restrict__ q_wbf, unsigned short* __restrict__ kv_wbf,
    unsigned short* __restrict__ sr_wbf, unsigned short* __restrict__ proj_wbf) {
  const int e = (blockIdx.x * 256 + threadIdx.x) * 8;
  if (e >= 196608 && e < 458752) {
    // sr_w: 8 consecutive src elems = (row, c0..c0+1, q0..3), c0 even
    const int off = e - 196608;
    const int row = off >> 10;
    const int wr = off & 1023;
    const int c0 = (wr >> 3) * 2;
    float4 a = *(const float4*)&sr_w[off];
    float4 b = *(const float4*)&sr_w[off + 4];
    const float v[8] = {a.x, a.y, a.z, a.w, b.x, b.y, b.z, b.w};
    const int base = (row >> 4) * 32;   // Kd/32 = 32
#pragma unroll
    for (int q = 0; q < 4; ++q) {
      const int unit = (base + q * 8 + (c0 >> 5)) * 64 + ((c0 >> 3) & 3) * 16 + (row & 15);
      *(unsigned*)&sr_wbf[unit * 8 + (c0 & 7)] = pk_bf16(v[q], v[4 + q]);
    }
    return;
  }
  const float* src; unsigned short* dst; int off; float sc = 1.f;
  if (e < 65536)       { src = q_w;    dst = q_wbf;    off = e;          sc = QSCALE; }
  else if (e < 196608) { src = kv_w;   dst = kv_wbf;   off = e - 65536; }
  else                 { src = proj_w; dst = proj_wbf; off = e - 458752; }
  const int row = off >> 8;
  const int col = off & 255;
  const int unit = ((row >> 4) * 8 + (col >> 5)) * 64 + ((col >> 3) & 3) * 16 + (row & 15);
  float4 a = *(const float4*)&src[off];
  float4 b = *(const float4*)&src[off + 4];
  a.x *= sc; a.y *= sc; a.z *= sc; a.w *= sc;
  b.x *= sc; b.y *= sc; b.z *= sc; b.w *= sc;
  *(short8*)&dst[unit * 8] = cvt8(a, b);
}

// X-tile LDS layout (tokens x 32 16B-units, 33-unit skew)
#define XU16(t, u) (((t) * 33 + (u)) * 8)

// ---------------------------------------------------------------------------
// SR-conv + LN + KV projection (unchanged -- control).
// Grid 256 x 512 thr (8 waves): conv 2 ct/wave full-K, LN on tid<256,
// KV waves 0-3 -> K, 4-7 -> V.
// ---------------------------------------------------------------------------
__global__ __launch_bounds__(512) void qconv_gemm(const float* __restrict__ x,
    const unsigned short* __restrict__ sr_wbf, const float* __restrict__ sr_b,
    const float* __restrict__ ln_g, const float* __restrict__ ln_b,
    const unsigned short* __restrict__ kv_wbf, const float* __restrict__ kv_b,
    unsigned short* __restrict__ kbf, unsigned short* __restrict__ vtbf) {
  __shared__ unsigned short sm[20736];
  const int tid = threadIdx.x, w = tid >> 6, ln = tid & 63;
  const int l15 = ln & 15, qd = ln >> 4;
  unsigned short* xs = sm + 16512;
  const int gt0 = blockIdx.x * 16;
  const int b = gt0 >> 10, tl = gt0 & 1023;
  const int ti = (tl & 1023) >> 5;
  const int cbase = 2 * (tl & 31);
#pragma unroll
  for (int it = 0; it < 4; ++it) {
    const int g = it * 512 + tid;     // 0..2047 16B-units
    const int xt = g >> 5, u = g & 31;
    const int di = xt >> 5, cj = xt & 31;
    const int row = (2 * ti + di) * 64 + cbase + cj;
    const float* s = &x[((size_t)b * NN + row) * CCH + u * 8];
    float4 a = *(const float4*)s;
    float4 b2 = *(const float4*)(s + 4);
    const int tk = cj >> 1, q = di * 2 + (cj & 1);
    *(short8*)(sm + (tk * 129 + q * 32 + u) * 8) = cvt8(a, b2);
  }
  __syncthreads();
  floatx4 cacc[2];
#pragma unroll
  for (int ct = 0; ct < 2; ++ct) for (int r = 0; r < 4; ++r) cacc[ct][r] = 0.f;
  const unsigned short* wbc = sr_wbf + ln * 8;
#pragma unroll
  for (int kc = 0; kc < 32; ++kc) {
    short8 xf = *(const short8*)(sm + (l15 * 129 + kc * 4 + qd) * 8);
#pragma unroll
    for (int ct = 0; ct < 2; ++ct) {
      short8 wf = *(const short8*)(wbc + ((size_t)((w * 2 + ct) * 32 + kc)) * 512);
      cacc[ct] = __builtin_amdgcn_mfma_f32_16x16x32_bf16(wf, xf, cacc[ct], 0, 0, 0);
    }
  }
  __syncthreads();
  float* ft = (float*)sm;
#pragma unroll
  for (int ct = 0; ct < 2; ++ct) {
    float4 o;
    o.x = cacc[ct][0]; o.y = cacc[ct][1]; o.z = cacc[ct][2]; o.w = cacc[ct][3];
    *(float4*)&ft[l15 * 260 + (w * 2 + ct) * 16 + qd * 4] = o;
  }
  __syncthreads();
  if (tid < 256) {
    const int tk = tid >> 4, l16 = tid & 15;
    float v[16];
    float4* vv = (float4*)v;
#pragma unroll
    for (int m = 0; m < 4; ++m) {
      float4 t = *(float4*)&ft[tk * 260 + l16 * 16 + m * 4];
      float4 sb = *(const float4*)&sr_b[l16 * 16 + m * 4];
      t.x += sb.x; t.y += sb.y; t.z += sb.z; t.w += sb.w;
      vv[m] = t;
    }
    float s1 = 0.f, s2 = 0.f;
#pragma unroll
    for (int i = 0; i < 16; ++i) { s1 += v[i]; s2 += v[i] * v[i]; }
#pragma unroll
    for (int off = 1; off < 16; off <<= 1) {
      s1 += __shfl_xor(s1, off);
      s2 += __shfl_xor(s2, off);
    }
    const float mu = s1 * (1.f / 256.f);
    const float rstd = rsqrtf(s2 * (1.f / 256.f) - mu * mu + EPS_LN);
#pragma unroll
    for (int m = 0; m < 2; ++m) {
      float4 ga = *(const float4*)&ln_g[l16 * 16 + m * 8];
      float4 gb = *(const float4*)&ln_g[l16 * 16 + m * 8 + 4];
      float4 ba = *(const float4*)&ln_b[l16 * 16 + m * 8];
      float4 bb = *(const float4*)&ln_b[l16 * 16 + m * 8 + 4];
      float4 oa, ob;
      oa.x = (vv[m * 2].x - mu) * rstd * ga.x + ba.x;
      oa.y = (vv[m * 2].y - mu) * rstd * ga.y + ba.y;
      oa.z = (vv[m * 2].z - mu) * rstd * ga.z + ba.z;
      oa.w = (vv[m * 2].w - mu) * rstd * ga.w + ba.w;
      ob.x = (vv[m * 2 + 1].x - mu) * rstd * gb.x + bb.x;
      ob.y = (vv[m * 2 + 1].y - mu) * rstd * gb.y + bb.y;
      ob.z = (vv[m * 2 + 1].z - mu) * rstd * gb.z + bb.z;
      ob.w = (vv[m * 2 + 1].w - mu) * rstd * gb.w + bb.w;
      *(short8*)(xs + XU16(tk, l16 * 2 + m)) = cvt8(oa, ob);
    }
  }
  __syncthreads();
  const bool isV = (w >= 4);
  const int c16b = (w & 3) * 4;
  floatx4 kacc[4];
#pragma unroll
  for (int ct = 0; ct < 4; ++ct) for (int r = 0; r < 4; ++r) kacc[ct][r] = 0.f;
  const unsigned short* wb = kv_wbf + (size_t)(isV ? 16 + c16b : c16b) * 4096 + ln * 8;
  if (!isV) {
#pragma unroll
    for (int kc = 0; kc < 8; ++kc) {
      short8 xf = *(const short8*)(xs + XU16(l15, kc * 4 + qd));
#pragma unroll
      for (int ct = 0; ct < 4; ++ct) {
        short8 wf = *(const short8*)(wb + ((size_t)ct * 4096 + kc * 512));
        kacc[ct] = __builtin_amdgcn_mfma_f32_16x16x32_bf16(wf, xf, kacc[ct], 0, 0, 0);
      }
    }
    const int tok = tl + l15;
#pragma unroll
    for (int ct = 0; ct < 4; ++ct) {
      const int ch = (c16b + ct) * 16 + qd * 4;
      float4 bb = *(const float4*)&kv_b[ch];
      uint2 u;
      u.x = pk_bf16(kacc[ct][0] + bb.x, kacc[ct][1] + bb.y);
      u.y = pk_bf16(kacc[ct][2] + bb.z, kacc[ct][3] + bb.w);
      const int h = ch >> 5, d0 = ch & 31;
      *(uint2*)&kbf[((size_t)(b * HEADS + h) * NKV + tok) * HD + d0] = u;
    }
  } else {
#pragma unroll
    for (int kc = 0; kc < 8; ++kc) {
      short8 xf = *(const short8*)(xs + XU16(l15, kc * 4 + qd));
#pragma unroll
      for (int ct = 0; ct < 4; ++ct) {
        short8 wf = *(const short8*)(wb + ((size_t)ct * 4096 + kc * 512));
        kacc[ct] = __builtin_amdgcn_mfma_f32_16x16x32_bf16(xf, wf, kacc[ct], 0, 0, 0);
      }
    }
    const int ccv = tl >> 6;
    const int base6 = (tl & 63) + qd * 4;
    const int kg = (base6 >> 5) & 1, kq = (base6 >> 3) & 3, j0 = base6 & 7;
#pragma unroll
    for (int ct = 0; ct < 4; ++ct) {
      const int vc = (w - 4) * 64 + ct * 16 + l15;
      const float bb = kv_b[vc + 256];
      uint2 u;
      u.x = pk_bf16(kacc[ct][0] + bb, kacc[ct][1] + bb);
      u.y = pk_bf16(kacc[ct][2] + bb, kacc[ct][3] + bb);
      const int hh = vc >> 5, d = vc & 31;
      const int half = d >> 4, dl = d & 15;
      const int unit = ((ccv * 2 + kg) * 2 + half) * 64 + kq * 16 + dl;
      *(uint2*)&vtbf[(size_t)(b * HEADS + hh) * 32768 + unit * 8 + j0] = u;
    }
  }
}

// ---------------------------------------------------------------------------
// FUSED Q-projection + flash attention + output projection (v13 = R7's v11
// + s_setprio around MFMA clusters).
// Block = 512 thr (8 waves), 64 tokens x all 8 heads; wave = head.
// Chunk loop is barrier-free: 8 waves run at independent phases, so
// setprio(1) on a wave's MFMA cluster lets the CU scheduler favor it over
// waves issuing loads/VALU (T5 regime: measured +4-7% on attn, null only in
// barrier-lockstep GEMM). R8 lesson: occupancy knobs don't pay here --
// the chain is dependency-bound, so help the scheduler, not the wave count.
// ---------------------------------------------------------------------------
__global__ __launch_bounds__(512) void attn_proj(
    const float* __restrict__ x,
    const unsigned short* __restrict__ q_wbf, const float* __restrict__ q_b,
    const unsigned short* __restrict__ kbf,
    const unsigned short* __restrict__ vtbf,
    const unsigned short* __restrict__ p_wbf, const float* __restrict__ p_b,
    float* __restrict__ out) {
  __shared__ unsigned short sm[72192];   // 144384 B: X[0,16896) P[16896,51712) Q[51712,72192)
  const int tid = threadIdx.x, w = tid >> 6, ln = tid & 63;
  const int l15 = ln & 15, qd = ln >> 4;
  const int g0 = blockIdx.x * 64;
  const int b = g0 >> 12;
  const int bh = b * HEADS + w;
  const unsigned short* kbase = kbf + (size_t)bh * NKV * HD;
  const unsigned short* vfb = vtbf + (size_t)bh * 32768;

  // ---- stage X (64 tokens, fp32 -> bf16, shared by all 8 heads) ----
  const float* Xg = x + (size_t)g0 * 256;
#pragma unroll
  for (int j = 0; j < 4; ++j) {
    const int idx = j * 512 + tid;
    const int tok = idx >> 5, u = idx & 31;
    float4 a = *(const float4*)(Xg + (size_t)tok * 256 + u * 8);
    float4 b2 = *(const float4*)(Xg + (size_t)tok * 256 + u * 8 + 4);
    *(short8*)(sm + XU16(tok, u)) = cvt8(a, b2);
  }
  __syncthreads();

  // ---- Q projection for own head: 64 tok x 32 ch, wave-private ----
  unsigned short* qls = sm + 51712 + w * 2560;   // 64 tok x 5-unit stride
  {
    floatx4 qacc[4][2];
#pragma unroll
    for (int tt = 0; tt < 4; ++tt)
#pragma unroll
      for (int ct = 0; ct < 2; ++ct)
        for (int r = 0; r < 4; ++r) qacc[tt][ct][r] = 0.f;
    const unsigned short* wb = q_wbf + (size_t)(2 * w) * 4096 + ln * 8;
#pragma unroll
    for (int kc = 0; kc < 8; ++kc) {
      short8 wf0 = *(const short8*)(wb + kc * 512);
      short8 wf1 = *(const short8*)(wb + (8 + kc) * 512);
#pragma unroll
      for (int tt = 0; tt < 4; ++tt) {
        short8 xf = *(const short8*)(sm + XU16(tt * 16 + l15, kc * 4 + qd));
        qacc[tt][0] = __builtin_amdgcn_mfma_f32_16x16x32_bf16(wf0, xf, qacc[tt][0], 0, 0, 0);
        qacc[tt][1] = __builtin_amdgcn_mfma_f32_16x16x32_bf16(wf1, xf, qacc[tt][1], 0, 0, 0);
      }
    }
#pragma unroll
    for (int tt = 0; tt < 4; ++tt)
#pragma unroll
      for (int ct = 0; ct < 2; ++ct) {
        const int ch = w * 32 + ct * 16 + qd * 4;
        float4 bb = *(const float4*)&q_b[ch];
        uint2 u;
        u.x = pk_bf16(qacc[tt][ct][0] + bb.x * QSCALE, qacc[tt][ct][1] + bb.y * QSCALE);
        u.y = pk_bf16(qacc[tt][ct][2] + bb.z * QSCALE, qacc[tt][ct][3] + bb.w * QSCALE);
        *(uint2*)(qls + ((tt * 16 + l15) * 5 + ct * 2 + (qd >> 1)) * 8 + (qd & 1) * 4) = u;
      }
  }
  // same-wave LDS round trip (lgkmcnt ordering; no barrier needed)
  short8 qf[4];
#pragma unroll
  for (int qt = 0; qt < 4; ++qt)
    qf[qt] = *(const short8*)(qls + ((qt * 16 + l15) * 5 + qd) * 8);

  const short8 ones = {16256, 16256, 16256, 16256, 16256, 16256, 16256, 16256};
  floatx4 a0[4], a1[4], al[4];
#pragma unroll
  for (int qt = 0; qt < 4; ++qt)
#pragma unroll
    for (int r = 0; r < 4; ++r) { a0[qt][r] = 0.f; a1[qt][r] = 0.f; al[qt][r] = 0.f; }
  const int pu = 2112 + w * 544;   // P base in 16B units (after X region)

  short8 kfA[4], vA[4], kfB[4], vB[4];
#define LOADKV(KF, VV, CC) do {                                               \
    const unsigned short* kp = kbase + ((size_t)(CC) * 64 + l15) * HD + qd * 8; \
    _Pragma("unroll")                                                          \
    for (int t = 0; t < 4; ++t) (KF)[t] = *(const short8*)(kp + t * 16 * HD);  \
    const unsigned short* vp = vfb + ((size_t)(CC) * 256 + ln) * 8;            \
    _Pragma("unroll")                                                          \
    for (int u = 0; u < 4; ++u) (VV)[u] = *(const short8*)(vp + u * 512);      \
  } while (0)

#define CHUNK(KF, VV) do {                                                     \
    _Pragma("unroll")                                                          \
    for (int qt = 0; qt < 4; ++qt) {                                           \
      const int pq = pu + qt * 136;                                            \
      floatx4 s[4];                                                            \
      __builtin_amdgcn_s_setprio(1);                                           \
      _Pragma("unroll")                                                        \
      for (int t = 0; t < 4; ++t) {                                            \
        floatx4 z; for (int r = 0; r < 4; ++r) z[r] = 0.f;                     \
        s[t] = __builtin_amdgcn_mfma_f32_16x16x32_bf16((KF)[t], qf[qt], z, 0, 0, 0); \
      }                                                                        \
      __builtin_amdgcn_s_setprio(0);                                           \
      _Pragma("unroll")                                                        \
      for (int t = 0; t < 4; ++t) {                                            \
        uint2 pk;                                                              \
        pk.x = pk_bf16(__builtin_amdgcn_exp2f(s[t][0]), __builtin_amdgcn_exp2f(s[t][1])); \
        pk.y = pk_bf16(__builtin_amdgcn_exp2f(s[t][2]), __builtin_amdgcn_exp2f(s[t][3])); \
        const int unit = pq + (t >> 1) * 68 + ((t & 1) * 2 + (qd >> 1)) * 16 + l15; \
        *(uint2*)(sm + unit * 8 + (qd & 1) * 4) = pk;                          \
      }                                                                        \
      __builtin_amdgcn_s_setprio(1);                                           \
      _Pragma("unroll")                                                        \
      for (int kg = 0; kg < 2; ++kg) {                                         \
        short8 pf = *(const short8*)(sm + (pq + kg * 68 + ln) * 8);            \
        a0[qt] = __builtin_amdgcn_mfma_f32_16x16x32_bf16((VV)[kg * 2], pf, a0[qt], 0, 0, 0);     \
        a1[qt] = __builtin_amdgcn_mfma_f32_16x16x32_bf16((VV)[kg * 2 + 1], pf, a1[qt], 0, 0, 0); \
        al[qt] = __builtin_amdgcn_mfma_f32_16x16x32_bf16(ones, pf, al[qt], 0, 0, 0);             \
      }                                                                        \
      __builtin_amdgcn_s_setprio(0);                                           \
    }                                                                          \
  } while (0)

  LOADKV(kfA, vA, 0);
  for (int cc = 0; cc < 16; cc += 2) {
    LOADKV(kfB, vB, cc + 1);
    CHUNK(kfA, vA);
    if (cc + 2 < 16) LOADKV(kfA, vA, cc + 2);
    CHUNK(kfB, vB);
  }
#undef LOADKV
#undef CHUNK

  // ---- all waves done with P and X -> stage normalized attn-out into X region
  __syncthreads();
#pragma unroll
  for (int qt = 0; qt < 4; ++qt) {
    const float inv = 1.f / al[qt][0];
    const int t = qt * 16 + l15;
    const int u0 = w * 4 + (qd >> 1);
    uint2 v0, v1;
    v0.x = pk_bf16(a0[qt][0] * inv, a0[qt][1] * inv);
    v0.y = pk_bf16(a0[qt][2] * inv, a0[qt][3] * inv);
    v1.x = pk_bf16(a1[qt][0] * inv, a1[qt][1] * inv);
    v1.y = pk_bf16(a1[qt][2] * inv, a1[qt][3] * inv);
    *(uint2*)(sm + XU16(t, u0) + (qd & 1) * 4) = v0;
    *(uint2*)(sm + XU16(t, u0 + 2) + (qd & 1) * 4) = v1;
  }
  __syncthreads();

  // ---- output projection in-block ----
  const int cb = w & 3, th = w >> 2;
  floatx4 pacc[2][4];
#pragma unroll
  for (int tt = 0; tt < 2; ++tt)
#pragma unroll
    for (int ct = 0; ct < 4; ++ct) for (int r = 0; r < 4; ++r) pacc[tt][ct][r] = 0.f;
  const unsigned short* wb = p_wbf + (size_t)(cb * 4) * 4096 + ln * 8;
#pragma unroll
  for (int kc = 0; kc < 8; ++kc) {
    short8 wf[4];
#pragma unroll
    for (int ct = 0; ct < 4; ++ct) wf[ct] = *(const short8*)(wb + (ct * 8 + kc) * 512);
#pragma unroll
    for (int tt = 0; tt < 2; ++tt) {
      short8 xf = *(const short8*)(sm + XU16(th * 32 + tt * 16 + l15, kc * 4 + qd));
#pragma unroll
      for (int ct = 0; ct < 4; ++ct)
        pacc[tt][ct] = __builtin_amdgcn_mfma_f32_16x16x32_bf16(wf[ct], xf, pacc[tt][ct], 0, 0, 0);
    }
  }
  const int chb = cb * 64;
#pragma unroll
  for (int tt = 0; tt < 2; ++tt) {
    const long tok = (long)g0 + th * 32 + tt * 16 + l15;
#pragma unroll
    for (int ct = 0; ct < 4; ++ct) {
      const int ch = chb + ct * 16 + qd * 4;
      float4 bb = *(const float4*)&p_b[ch];
      float4 o;
      o.x = pacc[tt][ct][0] + bb.x; o.y = pacc[tt][ct][1] + bb.y;
      o.z = pacc[tt][ct][2] + bb.z; o.w = pacc[tt][ct][3] + bb.w;
      *(float4*)&out[(size_t)tok * 256 + ch] = o;
    }
  }
}

// ---------------------------------------------------------------------------
extern "C" void kernel_launch(void* const* d_in, const int* in_sizes, int n_in,
                              void* d_out, int out_size, void* d_ws, size_t ws_size,
                              hipStream_t stream) {
  const float* x      = (const float*)d_in[0];
  const float* q_w    = (const float*)d_in[1];
  const float* q_b    = (const float*)d_in[2];
  const float* kv_w   = (const float*)d_in[3];
  const float* kv_b   = (const float*)d_in[4];
  const float* sr_w   = (const float*)d_in[5];
  const float* sr_b   = (const float*)d_in[6];
  const float* ln_g   = (const float*)d_in[7];
  const float* ln_b   = (const float*)d_in[8];
  const float* proj_w = (const float*)d_in[9];
  const float* proj_b = (const float*)d_in[10];
  float* out = (float*)d_out;

  char* base = (char*)d_ws;
  const size_t MB = 1048576;
  unsigned short* q_wbf    = (unsigned short*)(base);                 // 128 KB
  unsigned short* kv_wbf   = (unsigned short*)(base + 131072);        // 256 KB
  unsigned short* sr_wbf   = (unsigned short*)(base + 393216);        // 512 KB
  unsigned short* proj_wbf = (unsigned short*)(base + 917504);        // 128 KB
  unsigned short* k_bf     = (unsigned short*)(base + 9 * MB);        // 2 MB
  unsigned short* vt_bf    = (unsigned short*)(base + 11 * MB);       // 2 MB

  cast_weights<<<256, 256, 0, stream>>>(q_w, kv_w, sr_w, proj_w,
                                        q_wbf, kv_wbf, sr_wbf, proj_wbf);
  qconv_gemm<<<256, 512, 0, stream>>>(x, sr_wbf, sr_b, ln_g, ln_b,
                                      kv_wbf, kv_b, k_bf, vt_bf);
  attn_proj<<<256, 512, 0, stream>>>(x, q_wbf, q_b, k_bf, vt_bf,
                                     proj_wbf, proj_b, out);
}

// Round 10
// 140.190 us; speedup vs baseline: 1.0466x; 1.0005x over previous
//
#include <hip/hip_runtime.h>
#include <hip/hip_bf16.h>
#include <math.h>

#define BB 4
#define NN 4096
#define CCH 256
#define HEADS 8
#define HD 32
#define NKV 1024
#define EPS_LN 1e-5f

typedef short short8 __attribute__((ext_vector_type(8)));
typedef float floatx4 __attribute__((ext_vector_type(4)));

// scale = HD^-0.5 folded with log2(e): softmax runs in exp2 domain
#define QSCALE (0.17677669529663687f * 1.4426950408889634f)

__device__ __forceinline__ unsigned pk_bf16(float a, float b) {
  __hip_bfloat162 h = __float22bfloat162_rn(make_float2(a, b));
  unsigned u; __builtin_memcpy(&u, &h, 4); return u;
}

__device__ __forceinline__ short8 cvt8(float4 a, float4 b) {
  union { short8 s; unsigned u[4]; } r;
  r.u[0] = pk_bf16(a.x, a.y); r.u[1] = pk_bf16(a.z, a.w);
  r.u[2] = pk_bf16(b.x, b.y); r.u[3] = pk_bf16(b.z, b.w);
  return r.s;
}

// ---------------------------------------------------------------------------
// Cast weights fp32 -> bf16, FRAGMENT-MAJOR swizzle:
// unit(row,col) = ((row>>4)*(Kd/32) + (col>>5))*64 + ((col>>3)&3)*16 + (row&15)
// -> a wave's wf load is one contiguous 1KB segment. QSCALE folded into q_w.
// sr_w additionally gets K permuted to QUADRANT-MAJOR: col' = q*256 + c.
// ---------------------------------------------------------------------------
__global__ __launch_bounds__(256) void cast_weights(
    const float* __restrict__ q_w, const float* __restrict__ kv_w,
    const float* __restrict__ sr_w, const float* __restrict__ proj_w,
    unsigned short* __restrict__ q_wbf, unsigned short* __restrict__ kv_wbf,
    unsigned short* __restrict__ sr_wbf, unsigned short* __restrict__ proj_wbf) {
  const int e = (blockIdx.x * 256 + threadIdx.x) * 8;
  if (e >= 196608 && e < 458752) {
    // sr_w: 8 consecutive src elems = (row, c0..c0+1, q0..3), c0 even
    const int off = e - 196608;
    const int row = off >> 10;
    const int wr = off & 1023;
    const int c0 = (wr >> 3) * 2;
    float4 a = *(const float4*)&sr_w[off];
    float4 b = *(const float4*)&sr_w[off + 4];
    const float v[8] = {a.x, a.y, a.z, a.w, b.x, b.y, b.z, b.w};
    const int base = (row >> 4) * 32;   // Kd/32 = 32
#pragma unroll
    for (int q = 0; q < 4; ++q) {
      const int unit = (base + q * 8 + (c0 >> 5)) * 64 + ((c0 >> 3) & 3) * 16 + (row & 15);
      *(unsigned*)&sr_wbf[unit * 8 + (c0 & 7)] = pk_bf16(v[q], v[4 + q]);
    }
    return;
  }
  const float* src; unsigned short* dst; int off; float sc = 1.f;
  if (e < 65536)       { src = q_w;    dst = q_wbf;    off = e;          sc = QSCALE; }
  else if (e < 196608) { src = kv_w;   dst = kv_wbf;   off = e - 65536; }
  else                 { src = proj_w; dst = proj_wbf; off = e - 458752; }
  const int row = off >> 8;
  const int col = off & 255;
  const int unit = ((row >> 4) * 8 + (col >> 5)) * 64 + ((col >> 3) & 3) * 16 + (row & 15);
  float4 a = *(const float4*)&src[off];
  float4 b = *(const float4*)&src[off + 4];
  a.x *= sc; a.y *= sc; a.z *= sc; a.w *= sc;
  b.x *= sc; b.y *= sc; b.z *= sc; b.w *= sc;
  *(short8*)&dst[unit * 8] = cvt8(a, b);
}

// X-tile LDS layout (tokens x 32 16B-units, 33-unit skew)
#define XU16(t, u) (((t) * 33 + (u)) * 8)

// ---------------------------------------------------------------------------
// SR-conv + LN + KV projection (unchanged -- control).
// Grid 256 x 512 thr (8 waves): conv 2 ct/wave full-K, LN on tid<256,
// KV waves 0-3 -> K, 4-7 -> V.
// ---------------------------------------------------------------------------
__global__ __launch_bounds__(512) void qconv_gemm(const float* __restrict__ x,
    const unsigned short* __restrict__ sr_wbf, const float* __restrict__ sr_b,
    const float* __restrict__ ln_g, const float* __restrict__ ln_b,
    const unsigned short* __restrict__ kv_wbf, const float* __restrict__ kv_b,
    unsigned short* __restrict__ kbf, unsigned short* __restrict__ vtbf) {
  __shared__ unsigned short sm[20736];
  const int tid = threadIdx.x, w = tid >> 6, ln = tid & 63;
  const int l15 = ln & 15, qd = ln >> 4;
  unsigned short* xs = sm + 16512;
  const int gt0 = blockIdx.x * 16;
  const int b = gt0 >> 10, tl = gt0 & 1023;
  const int ti = (tl & 1023) >> 5;
  const int cbase = 2 * (tl & 31);
#pragma unroll
  for (int it = 0; it < 4; ++it) {
    const int g = it * 512 + tid;     // 0..2047 16B-units
    const int xt = g >> 5, u = g & 31;
    const int di = xt >> 5, cj = xt & 31;
    const int row = (2 * ti + di) * 64 + cbase + cj;
    const float* s = &x[((size_t)b * NN + row) * CCH + u * 8];
    float4 a = *(const float4*)s;
    float4 b2 = *(const float4*)(s + 4);
    const int tk = cj >> 1, q = di * 2 + (cj & 1);
    *(short8*)(sm + (tk * 129 + q * 32 + u) * 8) = cvt8(a, b2);
  }
  __syncthreads();
  floatx4 cacc[2];
#pragma unroll
  for (int ct = 0; ct < 2; ++ct) for (int r = 0; r < 4; ++r) cacc[ct][r] = 0.f;
  const unsigned short* wbc = sr_wbf + ln * 8;
#pragma unroll
  for (int kc = 0; kc < 32; ++kc) {
    short8 xf = *(const short8*)(sm + (l15 * 129 + kc * 4 + qd) * 8);
#pragma unroll
    for (int ct = 0; ct < 2; ++ct) {
      short8 wf = *(const short8*)(wbc + ((size_t)((w * 2 + ct) * 32 + kc)) * 512);
      cacc[ct] = __builtin_amdgcn_mfma_f32_16x16x32_bf16(wf, xf, cacc[ct], 0, 0, 0);
    }
  }
  __syncthreads();
  float* ft = (float*)sm;
#pragma unroll
  for (int ct = 0; ct < 2; ++ct) {
    float4 o;
    o.x = cacc[ct][0]; o.y = cacc[ct][1]; o.z = cacc[ct][2]; o.w = cacc[ct][3];
    *(float4*)&ft[l15 * 260 + (w * 2 + ct) * 16 + qd * 4] = o;
  }
  __syncthreads();
  if (tid < 256) {
    const int tk = tid >> 4, l16 = tid & 15;
    float v[16];
    float4* vv = (float4*)v;
#pragma unroll
    for (int m = 0; m < 4; ++m) {
      float4 t = *(float4*)&ft[tk * 260 + l16 * 16 + m * 4];
      float4 sb = *(const float4*)&sr_b[l16 * 16 + m * 4];
      t.x += sb.x; t.y += sb.y; t.z += sb.z; t.w += sb.w;
      vv[m] = t;
    }
    float s1 = 0.f, s2 = 0.f;
#pragma unroll
    for (int i = 0; i < 16; ++i) { s1 += v[i]; s2 += v[i] * v[i]; }
#pragma unroll
    for (int off = 1; off < 16; off <<= 1) {
      s1 += __shfl_xor(s1, off);
      s2 += __shfl_xor(s2, off);
    }
    const float mu = s1 * (1.f / 256.f);
    const float rstd = rsqrtf(s2 * (1.f / 256.f) - mu * mu + EPS_LN);
#pragma unroll
    for (int m = 0; m < 2; ++m) {
      float4 ga = *(const float4*)&ln_g[l16 * 16 + m * 8];
      float4 gb = *(const float4*)&ln_g[l16 * 16 + m * 8 + 4];
      float4 ba = *(const float4*)&ln_b[l16 * 16 + m * 8];
      float4 bb = *(const float4*)&ln_b[l16 * 16 + m * 8 + 4];
      float4 oa, ob;
      oa.x = (vv[m * 2].x - mu) * rstd * ga.x + ba.x;
      oa.y = (vv[m * 2].y - mu) * rstd * ga.y + ba.y;
      oa.z = (vv[m * 2].z - mu) * rstd * ga.z + ba.z;
      oa.w = (vv[m * 2].w - mu) * rstd * ga.w + ba.w;
      ob.x = (vv[m * 2 + 1].x - mu) * rstd * gb.x + bb.x;
      ob.y = (vv[m * 2 + 1].y - mu) * rstd * gb.y + bb.y;
      ob.z = (vv[m * 2 + 1].z - mu) * rstd * gb.z + bb.z;
      ob.w = (vv[m * 2 + 1].w - mu) * rstd * gb.w + bb.w;
      *(short8*)(xs + XU16(tk, l16 * 2 + m)) = cvt8(oa, ob);
    }
  }
  __syncthreads();
  const bool isV = (w >= 4);
  const int c16b = (w & 3) * 4;
  floatx4 kacc[4];
#pragma unroll
  for (int ct = 0; ct < 4; ++ct) for (int r = 0; r < 4; ++r) kacc[ct][r] = 0.f;
  const unsigned short* wb = kv_wbf + (size_t)(isV ? 16 + c16b : c16b) * 4096 + ln * 8;
  if (!isV) {
#pragma unroll
    for (int kc = 0; kc < 8; ++kc) {
      short8 xf = *(const short8*)(xs + XU16(l15, kc * 4 + qd));
#pragma unroll
      for (int ct = 0; ct < 4; ++ct) {
        short8 wf = *(const short8*)(wb + ((size_t)ct * 4096 + kc * 512));
        kacc[ct] = __builtin_amdgcn_mfma_f32_16x16x32_bf16(wf, xf, kacc[ct], 0, 0, 0);
      }
    }
    const int tok = tl + l15;
#pragma unroll
    for (int ct = 0; ct < 4; ++ct) {
      const int ch = (c16b + ct) * 16 + qd * 4;
      float4 bb = *(const float4*)&kv_b[ch];
      uint2 u;
      u.x = pk_bf16(kacc[ct][0] + bb.x, kacc[ct][1] + bb.y);
      u.y = pk_bf16(kacc[ct][2] + bb.z, kacc[ct][3] + bb.w);
      const int h = ch >> 5, d0 = ch & 31;
      *(uint2*)&kbf[((size_t)(b * HEADS + h) * NKV + tok) * HD + d0] = u;
    }
  } else {
#pragma unroll
    for (int kc = 0; kc < 8; ++kc) {
      short8 xf = *(const short8*)(xs + XU16(l15, kc * 4 + qd));
#pragma unroll
      for (int ct = 0; ct < 4; ++ct) {
        short8 wf = *(const short8*)(wb + ((size_t)ct * 4096 + kc * 512));
        kacc[ct] = __builtin_amdgcn_mfma_f32_16x16x32_bf16(xf, wf, kacc[ct], 0, 0, 0);
      }
    }
    const int ccv = tl >> 6;
    const int base6 = (tl & 63) + qd * 4;
    const int kg = (base6 >> 5) & 1, kq = (base6 >> 3) & 3, j0 = base6 & 7;
#pragma unroll
    for (int ct = 0; ct < 4; ++ct) {
      const int vc = (w - 4) * 64 + ct * 16 + l15;
      const float bb = kv_b[vc + 256];
      uint2 u;
      u.x = pk_bf16(kacc[ct][0] + bb, kacc[ct][1] + bb);
      u.y = pk_bf16(kacc[ct][2] + bb, kacc[ct][3] + bb);
      const int hh = vc >> 5, d = vc & 31;
      const int half = d >> 4, dl = d & 15;
      const int unit = ((ccv * 2 + kg) * 2 + half) * 64 + kq * 16 + dl;
      *(uint2*)&vtbf[(size_t)(b * HEADS + hh) * 32768 + unit * 8 + j0] = u;
    }
  }
}

// ---------------------------------------------------------------------------
// FUSED Q-projection + flash attention + output projection (v14 = v13 with
// PHASE-MAJOR chunk: all 16 QK MFMAs -> all 64 exp2+packs -> all 16 P-writes
// -> all P-reads + 24 PV MFMAs. R8/R9 showed occupancy & setprio don't fix
// the qt-serial dependency chain; phase-major gives each phase 16+ fully
// independent instructions of one class (MFMA pipe back-to-back, exp2 block
// pipelined, ONE lgkmcnt wait per chunk instead of four). +48 VGPR for
// s[4][4] -- free: kernel is LDS-bound at 1 blk/CU (2 waves/SIMD, cap 256).
// ---------------------------------------------------------------------------
__global__ __launch_bounds__(512) void attn_proj(
    const float* __restrict__ x,
    const unsigned short* __restrict__ q_wbf, const float* __restrict__ q_b,
    const unsigned short* __restrict__ kbf,
    const unsigned short* __restrict__ vtbf,
    const unsigned short* __restrict__ p_wbf, const float* __restrict__ p_b,
    float* __restrict__ out) {
  __shared__ unsigned short sm[72192];   // 144384 B: X[0,16896) P[16896,51712) Q[51712,72192)
  const int tid = threadIdx.x, w = tid >> 6, ln = tid & 63;
  const int l15 = ln & 15, qd = ln >> 4;
  const int g0 = blockIdx.x * 64;
  const int b = g0 >> 12;
  const int bh = b * HEADS + w;
  const unsigned short* kbase = kbf + (size_t)bh * NKV * HD;
  const unsigned short* vfb = vtbf + (size_t)bh * 32768;

  // ---- stage X (64 tokens, fp32 -> bf16, shared by all 8 heads) ----
  const float* Xg = x + (size_t)g0 * 256;
#pragma unroll
  for (int j = 0; j < 4; ++j) {
    const int idx = j * 512 + tid;
    const int tok = idx >> 5, u = idx & 31;
    float4 a = *(const float4*)(Xg + (size_t)tok * 256 + u * 8);
    float4 b2 = *(const float4*)(Xg + (size_t)tok * 256 + u * 8 + 4);
    *(short8*)(sm + XU16(tok, u)) = cvt8(a, b2);
  }
  __syncthreads();

  // ---- Q projection for own head: 64 tok x 32 ch, wave-private ----
  unsigned short* qls = sm + 51712 + w * 2560;   // 64 tok x 5-unit stride
  {
    floatx4 qacc[4][2];
#pragma unroll
    for (int tt = 0; tt < 4; ++tt)
#pragma unroll
      for (int ct = 0; ct < 2; ++ct)
        for (int r = 0; r < 4; ++r) qacc[tt][ct][r] = 0.f;
    const unsigned short* wb = q_wbf + (size_t)(2 * w) * 4096 + ln * 8;
#pragma unroll
    for (int kc = 0; kc < 8; ++kc) {
      short8 wf0 = *(const short8*)(wb + kc * 512);
      short8 wf1 = *(const short8*)(wb + (8 + kc) * 512);
#pragma unroll
      for (int tt = 0; tt < 4; ++tt) {
        short8 xf = *(const short8*)(sm + XU16(tt * 16 + l15, kc * 4 + qd));
        qacc[tt][0] = __builtin_amdgcn_mfma_f32_16x16x32_bf16(wf0, xf, qacc[tt][0], 0, 0, 0);
        qacc[tt][1] = __builtin_amdgcn_mfma_f32_16x16x32_bf16(wf1, xf, qacc[tt][1], 0, 0, 0);
      }
    }
#pragma unroll
    for (int tt = 0; tt < 4; ++tt)
#pragma unroll
      for (int ct = 0; ct < 2; ++ct) {
        const int ch = w * 32 + ct * 16 + qd * 4;
        float4 bb = *(const float4*)&q_b[ch];
        uint2 u;
        u.x = pk_bf16(qacc[tt][ct][0] + bb.x * QSCALE, qacc[tt][ct][1] + bb.y * QSCALE);
        u.y = pk_bf16(qacc[tt][ct][2] + bb.z * QSCALE, qacc[tt][ct][3] + bb.w * QSCALE);
        *(uint2*)(qls + ((tt * 16 + l15) * 5 + ct * 2 + (qd >> 1)) * 8 + (qd & 1) * 4) = u;
      }
  }
  // same-wave LDS round trip (lgkmcnt ordering; no barrier needed)
  short8 qf[4];
#pragma unroll
  for (int qt = 0; qt < 4; ++qt)
    qf[qt] = *(const short8*)(qls + ((qt * 16 + l15) * 5 + qd) * 8);

  const short8 ones = {16256, 16256, 16256, 16256, 16256, 16256, 16256, 16256};
  floatx4 a0[4], a1[4], al[4];
#pragma unroll
  for (int qt = 0; qt < 4; ++qt)
#pragma unroll
    for (int r = 0; r < 4; ++r) { a0[qt][r] = 0.f; a1[qt][r] = 0.f; al[qt][r] = 0.f; }
  const int pu = 2112 + w * 544;   // P base in 16B units (after X region)

  short8 kfA[4], vA[4], kfB[4], vB[4];
#define LOADKV(KF, VV, CC) do {                                               \
    const unsigned short* kp = kbase + ((size_t)(CC) * 64 + l15) * HD + qd * 8; \
    _Pragma("unroll")                                                          \
    for (int t = 0; t < 4; ++t) (KF)[t] = *(const short8*)(kp + t * 16 * HD);  \
    const unsigned short* vp = vfb + ((size_t)(CC) * 256 + ln) * 8;            \
    _Pragma("unroll")                                                          \
    for (int u = 0; u < 4; ++u) (VV)[u] = *(const short8*)(vp + u * 512);      \
  } while (0)

// PHASE-MAJOR chunk: maximal intra-phase ILP, one LDS-write->read wait.
#define CHUNK(KF, VV) do {                                                     \
    floatx4 s[4][4];                                                           \
    __builtin_amdgcn_s_setprio(1);                                             \
    _Pragma("unroll")                                                          \
    for (int qt = 0; qt < 4; ++qt) {                                           \
      _Pragma("unroll")                                                        \
      for (int t = 0; t < 4; ++t) {                                            \
        floatx4 z; for (int r = 0; r < 4; ++r) z[r] = 0.f;                     \
        s[qt][t] = __builtin_amdgcn_mfma_f32_16x16x32_bf16((KF)[t], qf[qt], z, 0, 0, 0); \
      }                                                                        \
    }                                                                          \
    __builtin_amdgcn_s_setprio(0);                                             \
    _Pragma("unroll")                                                          \
    for (int qt = 0; qt < 4; ++qt) {                                           \
      const int pq = pu + qt * 136;                                            \
      _Pragma("unroll")                                                        \
      for (int t = 0; t < 4; ++t) {                                            \
        uint2 pk;                                                              \
        pk.x = pk_bf16(__builtin_amdgcn_exp2f(s[qt][t][0]), __builtin_amdgcn_exp2f(s[qt][t][1])); \
        pk.y = pk_bf16(__builtin_amdgcn_exp2f(s[qt][t][2]), __builtin_amdgcn_exp2f(s[qt][t][3])); \
        const int unit = pq + (t >> 1) * 68 + ((t & 1) * 2 + (qd >> 1)) * 16 + l15; \
        *(uint2*)(sm + unit * 8 + (qd & 1) * 4) = pk;                          \
      }                                                                        \
    }                                                                          \
    __builtin_amdgcn_s_setprio(1);                                             \
    _Pragma("unroll")                                                          \
    for (int qt = 0; qt < 4; ++qt) {                                           \
      const int pq = pu + qt * 136;                                            \
      _Pragma("unroll")                                                        \
      for (int kg = 0; kg < 2; ++kg) {                                         \
        short8 pf = *(const short8*)(sm + (pq + kg * 68 + ln) * 8);            \
        a0[qt] = __builtin_amdgcn_mfma_f32_16x16x32_bf16((VV)[kg * 2], pf, a0[qt], 0, 0, 0);     \
        a1[qt] = __builtin_amdgcn_mfma_f32_16x16x32_bf16((VV)[kg * 2 + 1], pf, a1[qt], 0, 0, 0); \
        al[qt] = __builtin_amdgcn_mfma_f32_16x16x32_bf16(ones, pf, al[qt], 0, 0, 0);             \
      }                                                                        \
    }                                                                          \
    __builtin_amdgcn_s_setprio(0);                                             \
  } while (0)

  LOADKV(kfA, vA, 0);
  for (int cc = 0; cc < 16; cc += 2) {
    LOADKV(kfB, vB, cc + 1);
    CHUNK(kfA, vA);
    if (cc + 2 < 16) LOADKV(kfA, vA, cc + 2);
    CHUNK(kfB, vB);
  }
#undef LOADKV
#undef CHUNK

  // ---- all waves done with P and X -> stage normalized attn-out into X region
  __syncthreads();
#pragma unroll
  for (int qt = 0; qt < 4; ++qt) {
    const float inv = 1.f / al[qt][0];
    const int t = qt * 16 + l15;
    const int u0 = w * 4 + (qd >> 1);
    uint2 v0, v1;
    v0.x = pk_bf16(a0[qt][0] * inv, a0[qt][1] * inv);
    v0.y = pk_bf16(a0[qt][2] * inv, a0[qt][3] * inv);
    v1.x = pk_bf16(a1[qt][0] * inv, a1[qt][1] * inv);
    v1.y = pk_bf16(a1[qt][2] * inv, a1[qt][3] * inv);
    *(uint2*)(sm + XU16(t, u0) + (qd & 1) * 4) = v0;
    *(uint2*)(sm + XU16(t, u0 + 2) + (qd & 1) * 4) = v1;
  }
  __syncthreads();

  // ---- output projection in-block ----
  const int cb = w & 3, th = w >> 2;
  floatx4 pacc[2][4];
#pragma unroll
  for (int tt = 0; tt < 2; ++tt)
#pragma unroll
    for (int ct = 0; ct < 4; ++ct) for (int r = 0; r < 4; ++r) pacc[tt][ct][r] = 0.f;
  const unsigned short* wb = p_wbf + (size_t)(cb * 4) * 4096 + ln * 8;
#pragma unroll
  for (int kc = 0; kc < 8; ++kc) {
    short8 wf[4];
#pragma unroll
    for (int ct = 0; ct < 4; ++ct) wf[ct] = *(const short8*)(wb + (ct * 8 + kc) * 512);
#pragma unroll
    for (int tt = 0; tt < 2; ++tt) {
      short8 xf = *(const short8*)(sm + XU16(th * 32 + tt * 16 + l15, kc * 4 + qd));
#pragma unroll
      for (int ct = 0; ct < 4; ++ct)
        pacc[tt][ct] = __builtin_amdgcn_mfma_f32_16x16x32_bf16(wf[ct], xf, pacc[tt][ct], 0, 0, 0);
    }
  }
  const int chb = cb * 64;
#pragma unroll
  for (int tt = 0; tt < 2; ++tt) {
    const long tok = (long)g0 + th * 32 + tt * 16 + l15;
#pragma unroll
    for (int ct = 0; ct < 4; ++ct) {
      const int ch = chb + ct * 16 + qd * 4;
      float4 bb = *(const float4*)&p_b[ch];
      float4 o;
      o.x = pacc[tt][ct][0] + bb.x; o.y = pacc[tt][ct][1] + bb.y;
      o.z = pacc[tt][ct][2] + bb.z; o.w = pacc[tt][ct][3] + bb.w;
      *(float4*)&out[(size_t)tok * 256 + ch] = o;
    }
  }
}

// ---------------------------------------------------------------------------
extern "C" void kernel_launch(void* const* d_in, const int* in_sizes, int n_in,
                              void* d_out, int out_size, void* d_ws, size_t ws_size,
                              hipStream_t stream) {
  const float* x      = (const float*)d_in[0];
  const float* q_w    = (const float*)d_in[1];
  const float* q_b    = (const float*)d_in[2];
  const float* kv_w   = (const float*)d_in[3];
  const float* kv_b   = (const float*)d_in[4];
  const float* sr_w   = (const float*)d_in[5];
  const float* sr_b   = (const float*)d_in[6];
  const float* ln_g   = (const float*)d_in[7];
  const float* ln_b   = (const float*)d_in[8];
  const float* proj_w = (const float*)d_in[9];
  const float* proj_b = (const float*)d_in[10];
  float* out = (float*)d_out;

  char* base = (char*)d_ws;
  const size_t MB = 1048576;
  unsigned short* q_wbf    = (unsigned short*)(base);                 // 128 KB
  unsigned short* kv_wbf   = (unsigned short*)(base + 131072);        // 256 KB
  unsigned short* sr_wbf   = (unsigned short*)(base + 393216);        // 512 KB
  unsigned short* proj_wbf = (unsigned short*)(base + 917504);        // 128 KB
  unsigned short* k_bf     = (unsigned short*)(base + 9 * MB);        // 2 MB
  unsigned short* vt_bf    = (unsigned short*)(base + 11 * MB);       // 2 MB

  cast_weights<<<256, 256, 0, stream>>>(q_w, kv_w, sr_w, proj_w,
                                        q_wbf, kv_wbf, sr_wbf, proj_wbf);
  qconv_gemm<<<256, 512, 0, stream>>>(x, sr_wbf, sr_b, ln_g, ln_b,
                                      kv_wbf, kv_b, k_bf, vt_bf);
  attn_proj<<<256, 512, 0, stream>>>(x, q_wbf, q_b, k_bf, vt_bf,
                                     proj_wbf, proj_b, out);
}